// Round 15
// baseline (206.514 us; speedup 1.0000x reference)
//
#include <hip/hip_runtime.h>
#include <stdint.h>

// N=4096, B=32, LATENT=16, UNITS=64, NNZ=65536, K=2, M=5.
#define NN    4096
#define BB    32
#define NNZE  65536
#define WA    512      // pass-A diffusion width (16*B), row layout [b*16+f]
#define WD    512      // pass-B diffusion width (16*B), row layout [b*16+u']

typedef __attribute__((ext_vector_type(8))) short bf16x8;
typedef __attribute__((ext_vector_type(4))) float f32x4;

// ---------- bf16 helpers ----------
__device__ __forceinline__ float bf2f_lo(unsigned int u) {
    union { unsigned int x; float f; } c; c.x = u << 16; return c.f;
}
__device__ __forceinline__ float bf2f_hi(unsigned int u) {
    union { unsigned int x; float f; } c; c.x = u & 0xffff0000u; return c.f;
}
__device__ __forceinline__ float bf2f(unsigned int h) {
    union { unsigned int u; float f; } c; c.u = h << 16; return c.f;
}
__device__ __forceinline__ unsigned int f2bf(float f) {
    union { float ff; unsigned int u; } c; c.ff = f;
    return (c.u + 0x7fffu + ((c.u >> 16) & 1u)) >> 16;
}

// ---------- CSR build ----------
__global__ void hist2_kernel(const int* __restrict__ r1, const int* __restrict__ r2,
                             int* __restrict__ cnt1, int* __restrict__ cnt2) {
    int e = blockIdx.x * blockDim.x + threadIdx.x;   // < 2*NNZE
    if (e < NNZE) atomicAdd(&cnt1[r1[e]], 1);
    else          atomicAdd(&cnt2[r2[e - NNZE]], 1);
}

__global__ void scan2_kernel(int* cur1, int* rp1, int* cur2, int* rp2) {
    int* cur = (blockIdx.x == 0) ? cur1 : cur2;
    int* rp  = (blockIdx.x == 0) ? rp1  : rp2;
    __shared__ int part[256];
    int t = threadIdx.x;
    int base = t * 16;
    int loc[16];
    int s = 0;
#pragma unroll
    for (int i = 0; i < 16; ++i) { loc[i] = s; s += cur[base + i]; }
    part[t] = s;
    __syncthreads();
    for (int off = 1; off < 256; off <<= 1) {
        int v = 0;
        if (t >= off) v = part[t - off];
        __syncthreads();
        part[t] += v;
        __syncthreads();
    }
    int excl = (t == 0) ? 0 : part[t - 1];
#pragma unroll
    for (int i = 0; i < 16; ++i) rp[base + i] = excl + loc[i];
    __syncthreads();
#pragma unroll
    for (int i = 0; i < 16; ++i) cur[base + i] = rp[base + i];
    if (t == 255) rp[4096] = part[255];
}

// ---------- merged utility launch: scatter (CSR order) + transA + weight prep ----------
// blocks [0,512): scatter; [512,2560): transA (2 rows each); 2560: prep weights.
// Edge ep.x holds PRE-SCALED element offset col*WD (deletes per-edge mul in gather).
__global__ void util_kernel(const int* __restrict__ r1, const int* __restrict__ c1, const float* __restrict__ v1,
                            const int* __restrict__ r2, const int* __restrict__ c2, const float* __restrict__ v2,
                            int* __restrict__ cur1, int* __restrict__ cur2,
                            int2* __restrict__ ep1, int2* __restrict__ ep2,
                            const float* __restrict__ y, unsigned short* __restrict__ x0h,
                            const float* __restrict__ Wtheta, const float* __restrict__ Whid,
                            const float* __restrict__ Wout,
                            unsigned short* __restrict__ wpa, unsigned short* __restrict__ wpo) {
    int blk = blockIdx.x, t = threadIdx.x;
    if (blk < 512) {                       // ---- scatter packed (offset,val) into CSR order
        int e = blk * 256 + t;
        if (e < NNZE) {
            int pos = atomicAdd(&cur1[r1[e]], 1);
            ep1[pos] = make_int2(c1[e] * WD, __float_as_int(v1[e]));
        } else {
            int ee = e - NNZE;
            int pos = atomicAdd(&cur2[r2[ee]], 1);
            ep2[pos] = make_int2(c2[ee] * WD, __float_as_int(v2[ee]));
        }
    } else if (blk < 2560) {               // ---- transpose y -> [n][b*16+f] bf16
        int n = (blk - 512) * 2 + (t >> 7);
        int tt = t & 127;
        int b = tt & 31, q = tt >> 5;
        float4 y4 = *(const float4*)(y + (size_t)b * (NN * 16) + n * 16 + 4 * q);
        uint2 o;
        o.x = f2bf(y4.x) | (f2bf(y4.y) << 16);
        o.y = f2bf(y4.z) | (f2bf(y4.w) << 16);
        *(uint2*)(x0h + (size_t)n * WA + b * 16 + 4 * q) = o;
    } else {                               // ---- fold Chebyshev into GEMM1 weights, bf16-pack
        for (int i = t; i < 80 * 104; i += 256) {
            int col = i / 104, k = i - col * 104;
            float v = 0.f;
            if (k < 96) {
                int m = k >> 4, f = k & 15;
                if (m < 5) {
                    float w0, w2, w4, wm;
                    if (col < 16) {
                        w0 = Wtheta[(f * 5 + 0) * 16 + col];
                        w2 = Wtheta[(f * 5 + 2) * 16 + col];
                        w4 = Wtheta[(f * 5 + 4) * 16 + col];
                        wm = Wtheta[(f * 5 + m) * 16 + col];
                    } else {
                        int cc = col - 16;
                        w0 = Whid[(f * 5 + 0) * 64 + cc];
                        w2 = Whid[(f * 5 + 2) * 64 + cc];
                        w4 = Whid[(f * 5 + 4) * 64 + cc];
                        wm = Whid[(f * 5 + m) * 64 + cc];
                    }
                    v = (m == 0) ? w0 - w2 - w4 : (m == 2) ? 2.f * w2 : (m == 4) ? 2.f * w4 : wm;
                }
            }
            wpa[i] = (unsigned short)f2bf(v);
        }
        for (int i = t; i < 80 * 72; i += 256) {
            int col = i / 72, k = i - col * 72;
            float v = 0.f;
            if (k < 64) { int m = col >> 4, up = col & 15; v = Wout[(k * 5 + m) * 16 + up]; }
            wpo[i] = (unsigned short)f2bf(v);
        }
    }
}

// ---------- per-wave gather: wave-private LDS staging, no barriers ----------
// ep.x = element offset (col*WD) precomputed at scatter time.
__device__ __forceinline__ void gather_wave(const unsigned short* __restrict__ in,
                                            int beg, int end, const int2* __restrict__ ep,
                                            int lane, int* scol, float* sval, float* acc) {
    for (int i0 = beg; i0 < end; i0 += 64) {
        if (i0 + lane < end) { int2 e = ep[i0 + lane]; scol[lane] = e.x; sval[lane] = __int_as_float(e.y); }
        int nn = end - i0; if (nn > 64) nn = 64;
#pragma unroll 4
        for (int j = 0; j < nn; ++j) {
            const uint4* xr = (const uint4*)(in + scol[j]);
            uint4 xv = xr[lane];
            float v = sval[j];
            acc[0] += v * bf2f_lo(xv.x); acc[1] += v * bf2f_hi(xv.x);
            acc[2] += v * bf2f_lo(xv.y); acc[3] += v * bf2f_hi(xv.y);
            acc[4] += v * bf2f_lo(xv.z); acc[5] += v * bf2f_hi(xv.z);
            acc[6] += v * bf2f_lo(xv.w); acc[7] += v * bf2f_hi(xv.w);
        }
    }
}

// ---------- spmmD: 512-wide bf16 spmm, 2 rows/block (1/wave), XCD-chunked ----------
struct SpmmDesc {
    const unsigned short* in;     // [NN][512] bf16
    const unsigned short* prev;   // nullptr if beta==0
    float* outF;                  // exactly one of outF/outH non-null
    unsigned short* outH;
    const int* rp; const int2* ep;
    float alpha, beta;
};

__launch_bounds__(128)
__global__ void spmmD_kernel(SpmmDesc q0, SpmmDesc q1, SpmmDesc q2, SpmmDesc q3, int ninst) {
    __shared__ int  sscol[2][64];
    __shared__ float ssval[2][64];
    int t = threadIdx.x, w = t >> 6, lane = t & 63;
    int blk = blockIdx.x;                // grid = ninst*NN/2
    int xcd = blk & 7, idx = blk >> 3;
    int spx = 8 / ninst;                 // XCD slots per instance
    int inst = xcd / spx;                // each instance's 4MB source stays L2-resident per XCD
    int sub  = xcd - inst * spx;
    int row  = sub * (NN / spx) + idx * 2 + w;   // bijective over (inst,row)
    SpmmDesc q = (inst == 0) ? q0 : (inst == 1) ? q1 : (inst == 2) ? q2 : q3;
    int beg = q.rp[row], end = q.rp[row + 1];
    float acc[8];
#pragma unroll
    for (int k = 0; k < 8; ++k) acc[k] = 0.f;
    gather_wave(q.in, beg, end, q.ep, lane, sscol[w], ssval[w], acc);
    float r[8];
#pragma unroll
    for (int k = 0; k < 8; ++k) r[k] = q.alpha * acc[k];
    if (q.prev) {
        uint4 pv = ((const uint4*)(q.prev + (size_t)row * WD))[lane];
        r[0] += q.beta * bf2f_lo(pv.x); r[1] += q.beta * bf2f_hi(pv.x);
        r[2] += q.beta * bf2f_lo(pv.y); r[3] += q.beta * bf2f_hi(pv.y);
        r[4] += q.beta * bf2f_lo(pv.z); r[5] += q.beta * bf2f_hi(pv.z);
        r[6] += q.beta * bf2f_lo(pv.w); r[7] += q.beta * bf2f_hi(pv.w);
    }
    if (q.outF) {
        float* po = q.outF + (size_t)row * WD + lane * 8;
        *(float4*)(po)     = make_float4(r[0], r[1], r[2], r[3]);
        *(float4*)(po + 4) = make_float4(r[4], r[5], r[6], r[7]);
    } else {
        uint4 o;
        o.x = f2bf(r[0]) | (f2bf(r[1]) << 16);
        o.y = f2bf(r[2]) | (f2bf(r[3]) << 16);
        o.z = f2bf(r[4]) | (f2bf(r[5]) << 16);
        o.w = f2bf(r[6]) | (f2bf(r[7]) << 16);
        ((uint4*)(q.outH + (size_t)row * WD))[lane] = o;
    }
}

// ---------- fused projection: GEMM1 (theta,hid) -> tanh -> LDS transpose -> GEMM2 (Wout) ----------
// Weights pre-folded/packed by util_kernel; staged with coalesced uint4 copies.
// k-slot convention (both GEMMs): k = kt*32 + g*8 + j. D layout: col = lane&15 (=r), row = g*4 + reg.
__launch_bounds__(256)
__global__ void proj_fused(const unsigned short* __restrict__ xh,   // [5][NN][b*16+f] bf16
                           const unsigned short* __restrict__ wpa,  // [80][104] bf16
                           const unsigned short* __restrict__ wpo,  // [80][72] bf16
                           const float* __restrict__ b_hid,
                           float* __restrict__ theta,               // [NN][b*16+u']
                           float* __restrict__ d0,
                           unsigned short* __restrict__ dd1, unsigned short* __restrict__ dd2,
                           unsigned short* __restrict__ dd3, unsigned short* __restrict__ dd4) {
    __shared__ __align__(16) unsigned short sWa[80 * 104];   // 16.6 KB
    __shared__ __align__(16) unsigned short sWo[80 * 72];    // 11.3 KB
    __shared__ __align__(16) unsigned short sC[4][32 * 72];  // per-wave tanh(c) tile
    int t = threadIdx.x;
    for (int i = t; i < 1040; i += 256) ((uint4*)sWa)[i] = ((const uint4*)wpa)[i];
    for (int i = t; i < 720; i += 256) ((uint4*)sWo)[i] = ((const uint4*)wpo)[i];
    __syncthreads();
    int lane = t & 63, w = t >> 6;
    int r = lane & 15, g = lane >> 4;
    bf16x8 wfa[5][3];
#pragma unroll
    for (int ct = 0; ct < 5; ++ct)
#pragma unroll
        for (int kt = 0; kt < 3; ++kt)
            wfa[ct][kt] = *(const bf16x8*)(sWa + (ct * 16 + r) * 104 + kt * 32 + g * 8);
    float bh[4];
#pragma unroll
    for (int ct = 0; ct < 4; ++ct) bh[ct] = b_hid[ct * 16 + r];
    unsigned short* myC = (unsigned short*)sC[w];

    for (int i = 0; i < 2; ++i) {
        int n = blockIdx.x * 8 + w * 2 + i;
        // ---- GEMM1: [32 b][96 k] @ [96][80] ----
        f32x4 acc[2][5];
#pragma unroll
        for (int bt = 0; bt < 2; ++bt)
#pragma unroll
            for (int ct = 0; ct < 5; ++ct)
                acc[bt][ct] = (f32x4){0.f, 0.f, 0.f, 0.f};
#pragma unroll
        for (int kt = 0; kt < 3; ++kt) {
            bf16x8 a[2];
            int m = kt * 2 + (g >> 1);
#pragma unroll
            for (int bt = 0; bt < 2; ++bt) {
                bf16x8 av = {0, 0, 0, 0, 0, 0, 0, 0};
                if (m < 5)
                    av = *(const bf16x8*)(xh + ((size_t)m * NN + n) * WA
                                          + (bt * 16 + r) * 16 + (g & 1) * 8);
                a[bt] = av;
            }
#pragma unroll
            for (int bt = 0; bt < 2; ++bt)
#pragma unroll
                for (int ct = 0; ct < 5; ++ct)
                    acc[bt][ct] = __builtin_amdgcn_mfma_f32_16x16x32_bf16(
                        a[bt], wfa[ct][kt], acc[bt][ct], 0, 0, 0);
        }
        // theta store + tanh(c) -> per-wave LDS tile [b][u]
#pragma unroll
        for (int bt = 0; bt < 2; ++bt) {
#pragma unroll
            for (int reg = 0; reg < 4; ++reg) {
                int b = bt * 16 + g * 4 + reg;
                theta[(size_t)n * 512 + b * 16 + r] = acc[bt][0][reg];
            }
#pragma unroll
            for (int ct = 1; ct < 5; ++ct) {
                int u = (ct - 1) * 16 + r;
#pragma unroll
                for (int reg = 0; reg < 4; ++reg) {
                    int b = bt * 16 + g * 4 + reg;
                    myC[b * 72 + u] = (unsigned short)f2bf(tanhf(acc[bt][ct][reg] + bh[ct - 1]));
                }
            }
        }
        // ---- GEMM2: [32 b][64 k=u] @ [64][80 (m*16+u')] ----
        f32x4 acc2[2][5];
#pragma unroll
        for (int bt = 0; bt < 2; ++bt)
#pragma unroll
            for (int ct = 0; ct < 5; ++ct)
                acc2[bt][ct] = (f32x4){0.f, 0.f, 0.f, 0.f};
#pragma unroll
        for (int kt = 0; kt < 2; ++kt) {
            bf16x8 a2[2];
#pragma unroll
            for (int bt = 0; bt < 2; ++bt)
                a2[bt] = *(const bf16x8*)(myC + (bt * 16 + r) * 72 + kt * 32 + g * 8);
#pragma unroll
            for (int ct = 0; ct < 5; ++ct) {
                bf16x8 wo = *(const bf16x8*)(sWo + (ct * 16 + r) * 72 + kt * 32 + g * 8);
#pragma unroll
                for (int bt = 0; bt < 2; ++bt)
                    acc2[bt][ct] = __builtin_amdgcn_mfma_f32_16x16x32_bf16(
                        a2[bt], wo, acc2[bt][ct], 0, 0, 0);
            }
        }
        // d stores
#pragma unroll
        for (int bt = 0; bt < 2; ++bt) {
#pragma unroll
            for (int reg = 0; reg < 4; ++reg) {
                int b = bt * 16 + g * 4 + reg;
                d0[(size_t)n * WD + b * 16 + r] = acc2[bt][0][reg];
            }
#pragma unroll
            for (int ct = 1; ct < 5; ++ct) {
                unsigned short* dp = (ct == 1) ? dd1 : (ct == 2) ? dd2 : (ct == 3) ? dd3 : dd4;
#pragma unroll
                for (int reg = 0; reg < 4; ++reg) {
                    int b = bt * 16 + g * 4 + reg;
                    dp[(size_t)n * WD + b * 16 + r] = (unsigned short)f2bf(acc2[bt][ct][reg]);
                }
            }
        }
    }
}

// ---------- fused B2+final: 2 rows/block (1/wave), gather S1@g1 + S2@g3, combine ----------
// out = -sigmoid(theta+bl) * tanh(d0 - d2 - d4 + S1@g1 + S2@g3 + bl)
__launch_bounds__(128)
__global__ void finalspmm_kernel(const unsigned short* __restrict__ g1, const unsigned short* __restrict__ g3,
                                 const int* __restrict__ rp1, const int2* __restrict__ ep1,
                                 const int* __restrict__ rp2, const int2* __restrict__ ep2,
                                 const float* __restrict__ theta, const float* __restrict__ d0,
                                 const unsigned short* __restrict__ dd2, const unsigned short* __restrict__ dd4,
                                 const float* __restrict__ b_lat, float* __restrict__ out) {
    __shared__ int  sscol[2][64];
    __shared__ float ssval[2][64];
    int t = threadIdx.x, w = t >> 6, lane = t & 63;
    int blk = blockIdx.x;                          // grid = NN/2
    int row = (blk & 7) * 512 + (blk >> 3) * 2 + w;   // XCD-chunked, bijective
    float h[8];
#pragma unroll
    for (int k = 0; k < 8; ++k) h[k] = 0.f;
    gather_wave(g1, rp1[row], rp1[row + 1], ep1, lane, sscol[w], ssval[w], h);
    gather_wave(g3, rp2[row], rp2[row + 1], ep2, lane, sscol[w], ssval[w], h);
    // combine: i = lane*8 + j ; b = i>>4 = lane>>1 ; u = (lane&1)*8 + j
    size_t base = (size_t)row * WD + lane * 8;
    float4 dA = *(const float4*)(d0 + base);
    float4 dB = *(const float4*)(d0 + base + 4);
    uint4 p2 = *(const uint4*)(dd2 + base);
    uint4 p4 = *(const uint4*)(dd4 + base);
    float4 tA = *(const float4*)(theta + base);
    float4 tB = *(const float4*)(theta + base + 4);
    float4 blA = *(const float4*)(b_lat + (lane & 1) * 8);
    float4 blB = *(const float4*)(b_lat + (lane & 1) * 8 + 4);
    float tot[8], th[8];
    tot[0] = dA.x - bf2f_lo(p2.x) - bf2f_lo(p4.x) + h[0] + blA.x;
    tot[1] = dA.y - bf2f_hi(p2.x) - bf2f_hi(p4.x) + h[1] + blA.y;
    tot[2] = dA.z - bf2f_lo(p2.y) - bf2f_lo(p4.y) + h[2] + blA.z;
    tot[3] = dA.w - bf2f_hi(p2.y) - bf2f_hi(p4.y) + h[3] + blA.w;
    tot[4] = dB.x - bf2f_lo(p2.z) - bf2f_lo(p4.z) + h[4] + blB.x;
    tot[5] = dB.y - bf2f_hi(p2.z) - bf2f_hi(p4.z) + h[5] + blB.y;
    tot[6] = dB.z - bf2f_lo(p2.w) - bf2f_lo(p4.w) + h[6] + blB.z;
    tot[7] = dB.w - bf2f_hi(p2.w) - bf2f_hi(p4.w) + h[7] + blB.w;
    th[0] = tA.x + blA.x; th[1] = tA.y + blA.y; th[2] = tA.z + blA.z; th[3] = tA.w + blA.w;
    th[4] = tB.x + blB.x; th[5] = tB.y + blB.y; th[6] = tB.z + blB.z; th[7] = tB.w + blB.w;
    float res[8];
#pragma unroll
    for (int j = 0; j < 8; ++j)
        res[j] = -(1.f / (1.f + expf(-th[j]))) * tanhf(tot[j]);
    float* po = out + ((size_t)(lane >> 1) * NN + row) * 16 + (lane & 1) * 8;
    *(float4*)(po)     = make_float4(res[0], res[1], res[2], res[3]);
    *(float4*)(po + 4) = make_float4(res[4], res[5], res[6], res[7]);
}

extern "C" void kernel_launch(void* const* d_in, const int* in_sizes, int n_in,
                              void* d_out, int out_size, void* d_ws, size_t ws_size,
                              hipStream_t stream) {
    const float* y      = (const float*)d_in[1];
    const float* Wtheta = (const float*)d_in[2];
    const float* b_lat  = (const float*)d_in[3];
    const float* Whid   = (const float*)d_in[4];
    const float* b_hid  = (const float*)d_in[5];
    const float* Wout   = (const float*)d_in[6];
    const int*   r1     = (const int*)d_in[7];
    const int*   c1     = (const int*)d_in[8];
    const float* v1     = (const float*)d_in[9];
    const int*   r2     = (const int*)d_in[10];
    const int*   c2     = (const int*)d_in[11];
    const float* v2     = (const float*)d_in[12];
    float* out = (float*)d_out;

    // ---- workspace layout ----
    char* ws = (char*)d_ws;
    size_t off = 0;
    auto alloc = [&](size_t bytes) -> char* {
        char* p = ws + off;
        off += (bytes + 255) & ~(size_t)255;
        return p;
    };
    int*   rp1   = (int*)alloc(4097 * 4);
    int*   rp2   = (int*)alloc(4097 * 4);
    int*   cur1  = (int*)alloc(4096 * 4);            // cur1+cur2 contiguous (single memset)
    int*   cur2  = (int*)alloc(4096 * 4);
    int2*  ep1   = (int2*)alloc((size_t)NNZE * 8);
    int2*  ep2   = (int2*)alloc((size_t)NNZE * 8);
    unsigned short* wpa = (unsigned short*)alloc(80 * 104 * 2);           // folded GEMM1 panel
    unsigned short* wpo = (unsigned short*)alloc(80 * 72 * 2);            // GEMM2 panel
    unsigned short* xh = (unsigned short*)alloc((size_t)5 * NN * WA * 2); // 20 MB bf16 [m][n][512]
    float* theta = (float*)alloc((size_t)NN * 512 * 4);                   //  8 MB
    float* d0    = (float*)alloc((size_t)NN * WD * 4);                    //  8 MB
    unsigned short* dd1 = (unsigned short*)alloc((size_t)NN * WD * 2);    //  4 MB
    unsigned short* dd2 = (unsigned short*)alloc((size_t)NN * WD * 2);    //  4 MB
    unsigned short* dd3 = (unsigned short*)alloc((size_t)NN * WD * 2);    //  4 MB
    unsigned short* dd4 = (unsigned short*)alloc((size_t)NN * WD * 2);    //  4 MB
    unsigned short* g1  = (unsigned short*)alloc((size_t)NN * WD * 2);    //  4 MB
    unsigned short* g3  = (unsigned short*)alloc((size_t)NN * WD * 2);    //  4 MB
    if (off > ws_size) return;   // fail loudly if ws too small

    unsigned short* x0h = xh;
    unsigned short* x1h = xh + (size_t)1 * NN * WA;
    unsigned short* x2h = xh + (size_t)2 * NN * WA;   // holds y1 = S1@x1 (weights folded)
    unsigned short* x3h = xh + (size_t)3 * NN * WA;
    unsigned short* x4h = xh + (size_t)4 * NN * WA;   // holds y3 = S2@x3

    // ---- CSR build + merged utility (scatter + transA + weight prep) ----
    hipMemsetAsync(cur1, 0, 2 * 4096 * 4, stream);
    hist2_kernel<<<2 * NNZE / 256, 256, 0, stream>>>(r1, r2, cur1, cur2);
    scan2_kernel<<<2, 256, 0, stream>>>(cur1, rp1, cur2, rp2);
    util_kernel<<<2561, 256, 0, stream>>>(r1, c1, v1, r2, c2, v2, cur1, cur2, ep1, ep2,
                                          y, x0h, Wtheta, Whid, Wout, wpa, wpo);

    // ---- pass A: 2 narrow spmm launches ----
    {   // x1 = S1@x0, x3 = S2@x0
        SpmmDesc a0 = { x0h, nullptr, nullptr, x1h, rp1, ep1, 1.f, 0.f };
        SpmmDesc a1 = { x0h, nullptr, nullptr, x3h, rp2, ep2, 1.f, 0.f };
        spmmD_kernel<<<2 * NN / 2, 128, 0, stream>>>(a0, a1, a0, a1, 2);
    }
    {   // y1 = S1@x1, y3 = S2@x3  (Chebyshev folded into proj weights)
        SpmmDesc a0 = { x1h, nullptr, nullptr, x2h, rp1, ep1, 1.f, 0.f };
        SpmmDesc a1 = { x3h, nullptr, nullptr, x4h, rp2, ep2, 1.f, 0.f };
        spmmD_kernel<<<2 * NN / 2, 128, 0, stream>>>(a0, a1, a0, a1, 2);
    }

    // ---- fused projection: theta + tanh(hid) -> d0..d4 in one kernel ----
    proj_fused<<<NN / 8, 256, 0, stream>>>(xh, wpa, wpo, b_hid,
                                           theta, d0, dd1, dd2, dd3, dd4);

    // ---- pass B (commuted + telescoped): one spmm round, then fused final ----
    {   // g1 = 2*S1@d2 + d1 (bf16), g3 = 2*S2@d4 + d3 (bf16)
        SpmmDesc a0 = { dd2, dd1, nullptr, g1, rp1, ep1, 2.f, 1.f };
        SpmmDesc a1 = { dd4, dd3, nullptr, g3, rp2, ep2, 2.f, 1.f };
        spmmD_kernel<<<2 * NN / 2, 128, 0, stream>>>(a0, a1, a0, a1, 2);
    }
    // fused: out = -sigmoid(theta+bl)*tanh(d0 - d2 - d4 + S1@g1 + S2@g3 + bl)
    finalspmm_kernel<<<NN / 2, 128, 0, stream>>>(g1, g3, rp1, ep1, rp2, ep2,
                                                 theta, d0, dd2, dd4, b_lat, out);
}

// Round 18
// 204.004 us; speedup vs baseline: 1.0123x; 1.0123x over previous
//
#include <hip/hip_runtime.h>
#include <hip/hip_cooperative_groups.h>
#include <stdint.h>

namespace cg = cooperative_groups;

// N=4096, B=32, LATENT=16, UNITS=64, NNZ=65536, K=2, M=5.
#define NN    4096
#define BB    32
#define NNZE  65536
#define WA    512      // pass-A diffusion width (16*B), row layout [b*16+f]
#define WD    512      // pass-B diffusion width (16*B), row layout [b*16+u']
#define MGRID 512      // cooperative grid (2 blocks/CU on 256 CUs)

typedef __attribute__((ext_vector_type(8))) short bf16x8;
typedef __attribute__((ext_vector_type(4))) float f32x4;

// ---------- bf16 helpers ----------
__device__ __forceinline__ float bf2f_lo(unsigned int u) {
    union { unsigned int x; float f; } c; c.x = u << 16; return c.f;
}
__device__ __forceinline__ float bf2f_hi(unsigned int u) {
    union { unsigned int x; float f; } c; c.x = u & 0xffff0000u; return c.f;
}
__device__ __forceinline__ float bf2f(unsigned int h) {
    union { unsigned int u; float f; } c; c.u = h << 16; return c.f;
}
__device__ __forceinline__ unsigned int f2bf(float f) {
    union { float ff; unsigned int u; } c; c.ff = f;
    return (c.u + 0x7fffu + ((c.u >> 16) & 1u)) >> 16;
}

// ================= shared device bodies =================

__device__ __forceinline__ void scan_dev(int* cur, int* rp, int* part, int t) {
    int base = t * 16;
    int loc[16];
    int s = 0;
#pragma unroll
    for (int i = 0; i < 16; ++i) { loc[i] = s; s += cur[base + i]; }
    part[t] = s;
    __syncthreads();
    for (int off = 1; off < 256; off <<= 1) {
        int v = 0;
        if (t >= off) v = part[t - off];
        __syncthreads();
        part[t] += v;
        __syncthreads();
    }
    int excl = (t == 0) ? 0 : part[t - 1];
#pragma unroll
    for (int i = 0; i < 16; ++i) rp[base + i] = excl + loc[i];
    __syncthreads();
#pragma unroll
    for (int i = 0; i < 16; ++i) cur[base + i] = rp[base + i];
    if (t == 255) rp[4096] = part[255];
}

__device__ __forceinline__ void transA_item(int item, const float* y, unsigned short* x0h) {
    int n = item >> 7, tt = item & 127;
    int b = tt & 31, q = tt >> 5;
    float4 y4 = *(const float4*)(y + (size_t)b * (NN * 16) + n * 16 + 4 * q);
    uint2 o;
    o.x = f2bf(y4.x) | (f2bf(y4.y) << 16);
    o.y = f2bf(y4.z) | (f2bf(y4.w) << 16);
    *(uint2*)(x0h + (size_t)n * WA + b * 16 + 4 * q) = o;
}

__device__ __forceinline__ void prep_dev(int t, const float* Wtheta, const float* Whid,
                                         const float* Wout,
                                         unsigned short* wpa, unsigned short* wpo) {
    for (int i = t; i < 80 * 104; i += 256) {
        int col = i / 104, k = i - col * 104;
        float v = 0.f;
        if (k < 96) {
            int m = k >> 4, f = k & 15;
            if (m < 5) {
                float w0, w2, w4, wm;
                if (col < 16) {
                    w0 = Wtheta[(f * 5 + 0) * 16 + col];
                    w2 = Wtheta[(f * 5 + 2) * 16 + col];
                    w4 = Wtheta[(f * 5 + 4) * 16 + col];
                    wm = Wtheta[(f * 5 + m) * 16 + col];
                } else {
                    int cc = col - 16;
                    w0 = Whid[(f * 5 + 0) * 64 + cc];
                    w2 = Whid[(f * 5 + 2) * 64 + cc];
                    w4 = Whid[(f * 5 + 4) * 64 + cc];
                    wm = Whid[(f * 5 + m) * 64 + cc];
                }
                v = (m == 0) ? w0 - w2 - w4 : (m == 2) ? 2.f * w2 : (m == 4) ? 2.f * w4 : wm;
            }
        }
        wpa[i] = (unsigned short)f2bf(v);
    }
    for (int i = t; i < 80 * 72; i += 256) {
        int col = i / 72, k = i - col * 72;
        float v = 0.f;
        if (k < 64) { int m = col >> 4, up = col & 15; v = Wout[(k * 5 + m) * 16 + up]; }
        wpo[i] = (unsigned short)f2bf(v);
    }
}

// per-wave gather: wave-private LDS staging, no barriers; ep.x = col*WD prescaled
__device__ __forceinline__ void gather_wave(const unsigned short* __restrict__ in,
                                            int beg, int end, const int2* __restrict__ ep,
                                            int lane, int* scol, float* sval, float* acc) {
    for (int i0 = beg; i0 < end; i0 += 64) {
        if (i0 + lane < end) { int2 e = ep[i0 + lane]; scol[lane] = e.x; sval[lane] = __int_as_float(e.y); }
        int nn = end - i0; if (nn > 64) nn = 64;
#pragma unroll 4
        for (int j = 0; j < nn; ++j) {
            const uint4* xr = (const uint4*)(in + scol[j]);
            uint4 xv = xr[lane];
            float v = sval[j];
            acc[0] += v * bf2f_lo(xv.x); acc[1] += v * bf2f_hi(xv.x);
            acc[2] += v * bf2f_lo(xv.y); acc[3] += v * bf2f_hi(xv.y);
            acc[4] += v * bf2f_lo(xv.z); acc[5] += v * bf2f_hi(xv.z);
            acc[6] += v * bf2f_lo(xv.w); acc[7] += v * bf2f_hi(xv.w);
        }
    }
}

// one spmm row: out(bf16) = alpha*(S@in)[row] + beta*prev[row]
__device__ __forceinline__ void spmm_row(const unsigned short* in, const unsigned short* prev,
                                         unsigned short* outH,
                                         const int* rp, const int2* ep, float alpha, float beta,
                                         int row, int lane, int* scol, float* sval) {
    int beg = rp[row], end = rp[row + 1];
    float acc[8];
#pragma unroll
    for (int k = 0; k < 8; ++k) acc[k] = 0.f;
    gather_wave(in, beg, end, ep, lane, scol, sval, acc);
    float r[8];
#pragma unroll
    for (int k = 0; k < 8; ++k) r[k] = alpha * acc[k];
    if (prev) {
        uint4 pv = ((const uint4*)(prev + (size_t)row * WD))[lane];
        r[0] += beta * bf2f_lo(pv.x); r[1] += beta * bf2f_hi(pv.x);
        r[2] += beta * bf2f_lo(pv.y); r[3] += beta * bf2f_hi(pv.y);
        r[4] += beta * bf2f_lo(pv.z); r[5] += beta * bf2f_hi(pv.z);
        r[6] += beta * bf2f_lo(pv.w); r[7] += beta * bf2f_hi(pv.w);
    }
    uint4 o;
    o.x = f2bf(r[0]) | (f2bf(r[1]) << 16);
    o.y = f2bf(r[2]) | (f2bf(r[3]) << 16);
    o.z = f2bf(r[4]) | (f2bf(r[5]) << 16);
    o.w = f2bf(r[6]) | (f2bf(r[7]) << 16);
    ((uint4*)(outH + (size_t)row * WD))[lane] = o;
}

// proj body for one n (wave-local; myC is this wave's LDS tile)
__device__ __forceinline__ void proj_one(int n, int r, int g,
                                         const bf16x8 (&wfa)[5][3], const float (&bh)[4],
                                         const unsigned short* sWo, unsigned short* myC,
                                         const unsigned short* xh,
                                         float* theta, float* d0,
                                         unsigned short* dd1, unsigned short* dd2,
                                         unsigned short* dd3, unsigned short* dd4) {
    // ---- GEMM1: [32 b][96 k] @ [96][80] ----
    f32x4 acc[2][5];
#pragma unroll
    for (int bt = 0; bt < 2; ++bt)
#pragma unroll
        for (int ct = 0; ct < 5; ++ct)
            acc[bt][ct] = (f32x4){0.f, 0.f, 0.f, 0.f};
#pragma unroll
    for (int kt = 0; kt < 3; ++kt) {
        bf16x8 a[2];
        int m = kt * 2 + (g >> 1);
#pragma unroll
        for (int bt = 0; bt < 2; ++bt) {
            bf16x8 av = {0, 0, 0, 0, 0, 0, 0, 0};
            if (m < 5)
                av = *(const bf16x8*)(xh + ((size_t)m * NN + n) * WA
                                      + (bt * 16 + r) * 16 + (g & 1) * 8);
            a[bt] = av;
        }
#pragma unroll
        for (int bt = 0; bt < 2; ++bt)
#pragma unroll
            for (int ct = 0; ct < 5; ++ct)
                acc[bt][ct] = __builtin_amdgcn_mfma_f32_16x16x32_bf16(
                    a[bt], wfa[ct][kt], acc[bt][ct], 0, 0, 0);
    }
    // theta store + tanh(c) -> per-wave LDS tile [b][u]
#pragma unroll
    for (int bt = 0; bt < 2; ++bt) {
#pragma unroll
        for (int reg = 0; reg < 4; ++reg) {
            int b = bt * 16 + g * 4 + reg;
            theta[(size_t)n * 512 + b * 16 + r] = acc[bt][0][reg];
        }
#pragma unroll
        for (int ct = 1; ct < 5; ++ct) {
            int u = (ct - 1) * 16 + r;
#pragma unroll
            for (int reg = 0; reg < 4; ++reg) {
                int b = bt * 16 + g * 4 + reg;
                myC[b * 72 + u] = (unsigned short)f2bf(tanhf(acc[bt][ct][reg] + bh[ct - 1]));
            }
        }
    }
    // ---- GEMM2: [32 b][64 k=u] @ [64][80 (m*16+u')] ----
    f32x4 acc2[2][5];
#pragma unroll
    for (int bt = 0; bt < 2; ++bt)
#pragma unroll
        for (int ct = 0; ct < 5; ++ct)
            acc2[bt][ct] = (f32x4){0.f, 0.f, 0.f, 0.f};
#pragma unroll
    for (int kt = 0; kt < 2; ++kt) {
        bf16x8 a2[2];
#pragma unroll
        for (int bt = 0; bt < 2; ++bt)
            a2[bt] = *(const bf16x8*)(myC + (bt * 16 + r) * 72 + kt * 32 + g * 8);
#pragma unroll
        for (int ct = 0; ct < 5; ++ct) {
            bf16x8 wo = *(const bf16x8*)(sWo + (ct * 16 + r) * 72 + kt * 32 + g * 8);
#pragma unroll
            for (int bt = 0; bt < 2; ++bt)
                acc2[bt][ct] = __builtin_amdgcn_mfma_f32_16x16x32_bf16(
                    a2[bt], wo, acc2[bt][ct], 0, 0, 0);
        }
    }
#pragma unroll
    for (int bt = 0; bt < 2; ++bt) {
#pragma unroll
        for (int reg = 0; reg < 4; ++reg) {
            int b = bt * 16 + g * 4 + reg;
            d0[(size_t)n * WD + b * 16 + r] = acc2[bt][0][reg];
        }
#pragma unroll
        for (int ct = 1; ct < 5; ++ct) {
            unsigned short* dp = (ct == 1) ? dd1 : (ct == 2) ? dd2 : (ct == 3) ? dd3 : dd4;
#pragma unroll
            for (int reg = 0; reg < 4; ++reg) {
                int b = bt * 16 + g * 4 + reg;
                dp[(size_t)n * WD + b * 16 + r] = (unsigned short)f2bf(acc2[bt][ct][reg]);
            }
        }
    }
}

// final-combine body for one row
__device__ __forceinline__ void final_row(int row, int lane, int* scol, float* sval,
                                          const unsigned short* g1, const unsigned short* g3,
                                          const int* rp1, const int2* ep1,
                                          const int* rp2, const int2* ep2,
                                          const float* theta, const float* d0,
                                          const unsigned short* dd2, const unsigned short* dd4,
                                          const float* b_lat, float* out) {
    float h[8];
#pragma unroll
    for (int k = 0; k < 8; ++k) h[k] = 0.f;
    gather_wave(g1, rp1[row], rp1[row + 1], ep1, lane, scol, sval, h);
    gather_wave(g3, rp2[row], rp2[row + 1], ep2, lane, scol, sval, h);
    size_t base = (size_t)row * WD + lane * 8;
    float4 dA = *(const float4*)(d0 + base);
    float4 dB = *(const float4*)(d0 + base + 4);
    uint4 p2 = *(const uint4*)(dd2 + base);
    uint4 p4 = *(const uint4*)(dd4 + base);
    float4 tA = *(const float4*)(theta + base);
    float4 tB = *(const float4*)(theta + base + 4);
    float4 blA = *(const float4*)(b_lat + (lane & 1) * 8);
    float4 blB = *(const float4*)(b_lat + (lane & 1) * 8 + 4);
    float tot[8], th[8];
    tot[0] = dA.x - bf2f_lo(p2.x) - bf2f_lo(p4.x) + h[0] + blA.x;
    tot[1] = dA.y - bf2f_hi(p2.x) - bf2f_hi(p4.x) + h[1] + blA.y;
    tot[2] = dA.z - bf2f_lo(p2.y) - bf2f_lo(p4.y) + h[2] + blA.z;
    tot[3] = dA.w - bf2f_hi(p2.y) - bf2f_hi(p4.y) + h[3] + blA.w;
    tot[4] = dB.x - bf2f_lo(p2.z) - bf2f_lo(p4.z) + h[4] + blB.x;
    tot[5] = dB.y - bf2f_hi(p2.z) - bf2f_hi(p4.z) + h[5] + blB.y;
    tot[6] = dB.z - bf2f_lo(p2.w) - bf2f_lo(p4.w) + h[6] + blB.z;
    tot[7] = dB.w - bf2f_hi(p2.w) - bf2f_hi(p4.w) + h[7] + blB.w;
    th[0] = tA.x + blA.x; th[1] = tA.y + blA.y; th[2] = tA.z + blA.z; th[3] = tA.w + blA.w;
    th[4] = tB.x + blB.x; th[5] = tB.y + blB.y; th[6] = tB.z + blB.z; th[7] = tB.w + blB.w;
    float res[8];
#pragma unroll
    for (int j = 0; j < 8; ++j)
        res[j] = -(1.f / (1.f + expf(-th[j]))) * tanhf(tot[j]);
    float* po = out + ((size_t)(lane >> 1) * NN + row) * 16 + (lane & 1) * 8;
    *(float4*)(po)     = make_float4(res[0], res[1], res[2], res[3]);
    *(float4*)(po + 4) = make_float4(res[4], res[5], res[6], res[7]);
}

// ================= cooperative mega-kernel =================

struct MegaArgs {
    const int *r1, *c1; const float* v1;
    const int *r2, *c2; const float* v2;
    int *cur1, *cur2, *rp1, *rp2;
    int2 *ep1, *ep2;
    const float *y, *Wtheta, *Whid, *Wout, *b_hid, *b_lat;
    unsigned short *x0h, *x1h, *x2h, *x3h, *x4h, *wpa, *wpo;
    float *theta, *d0;
    unsigned short *dd1, *dd2, *dd3, *dd4, *g1, *g3;
    float* out;
};

__launch_bounds__(256, 2)
__global__ void mega_kernel(MegaArgs a) {
    cg::grid_group grid = cg::this_grid();
    __shared__ int part[256];
    __shared__ int  sscol[4][64];
    __shared__ float ssval[4][64];
    __shared__ __align__(16) unsigned short sWa[80 * 104];
    __shared__ __align__(16) unsigned short sWo[80 * 72];
    __shared__ __align__(16) unsigned short sC[4][32 * 72];
    int blk = blockIdx.x, t = threadIdx.x;
    int w = t >> 6, lane = t & 63;
    int gw = blk * 4 + w;          // 0..2047
    int* scol = sscol[w];
    float* sval = ssval[w];

    // ---- P0: histogram (131072 edges, one per thread) ----
    {
        int e = blk * 256 + t;
        if (e < NNZE) atomicAdd(&a.cur1[a.r1[e]], 1);
        else          atomicAdd(&a.cur2[a.r2[e - NNZE]], 1);
    }
    grid.sync();
    // ---- P1: scan (blocks 0,1) ----
    if (blk < 2) scan_dev(blk == 0 ? a.cur1 : a.cur2, blk == 0 ? a.rp1 : a.rp2, part, t);
    grid.sync();
    // ---- P2: scatter + transA + weight prep ----
    {
        int e = blk * 256 + t;
        if (e < NNZE) {
            int pos = atomicAdd(&a.cur1[a.r1[e]], 1);
            a.ep1[pos] = make_int2(a.c1[e] * WD, __float_as_int(a.v1[e]));
        } else {
            int ee = e - NNZE;
            int pos = atomicAdd(&a.cur2[a.r2[ee]], 1);
            a.ep2[pos] = make_int2(a.c2[ee] * WD, __float_as_int(a.v2[ee]));
        }
#pragma unroll
        for (int rep = 0; rep < 4; ++rep)
            transA_item(e + rep * 131072, a.y, a.x0h);
        if (blk == MGRID - 1) prep_dev(t, a.Wtheta, a.Whid, a.Wout, a.wpa, a.wpo);
    }
    grid.sync();
    // ---- P3: x1 = S1@x0, x3 = S2@x0 (4 rows/wave, XCD-chunked) ----
    {
        int xcd = blk & 7, inst = xcd >> 2, sub = xcd & 3;
        int local = (blk >> 3) * 4 + w;          // 0..255
#pragma unroll
        for (int rr = 0; rr < 4; ++rr) {
            int row = sub * 1024 + local * 4 + rr;
            if (inst == 0) spmm_row(a.x0h, nullptr, a.x1h, a.rp1, a.ep1, 1.f, 0.f, row, lane, scol, sval);
            else           spmm_row(a.x0h, nullptr, a.x3h, a.rp2, a.ep2, 1.f, 0.f, row, lane, scol, sval);
        }
    }
    grid.sync();
    // ---- P4: y1 = S1@x1, y3 = S2@x3 (Chebyshev folded into proj weights) ----
    {
        int xcd = blk & 7, inst = xcd >> 2, sub = xcd & 3;
        int local = (blk >> 3) * 4 + w;
#pragma unroll
        for (int rr = 0; rr < 4; ++rr) {
            int row = sub * 1024 + local * 4 + rr;
            if (inst == 0) spmm_row(a.x1h, nullptr, a.x2h, a.rp1, a.ep1, 1.f, 0.f, row, lane, scol, sval);
            else           spmm_row(a.x3h, nullptr, a.x4h, a.rp2, a.ep2, 1.f, 0.f, row, lane, scol, sval);
        }
    }
    grid.sync();
    // ---- P5: fused projection (2 n per wave) ----
    {
        for (int i = t; i < 1040; i += 256) ((uint4*)sWa)[i] = ((const uint4*)a.wpa)[i];
        for (int i = t; i < 720; i += 256) ((uint4*)sWo)[i] = ((const uint4*)a.wpo)[i];
        __syncthreads();
        int r = lane & 15, g = lane >> 4;
        bf16x8 wfa[5][3];
#pragma unroll
        for (int ct = 0; ct < 5; ++ct)
#pragma unroll
            for (int kt = 0; kt < 3; ++kt)
                wfa[ct][kt] = *(const bf16x8*)(sWa + (ct * 16 + r) * 104 + kt * 32 + g * 8);
        float bh[4];
#pragma unroll
        for (int ct = 0; ct < 4; ++ct) bh[ct] = a.b_hid[ct * 16 + r];
        unsigned short* myC = (unsigned short*)sC[w];
        for (int i = 0; i < 2; ++i)
            proj_one(gw * 2 + i, r, g, wfa, bh, sWo, myC, a.x0h,
                     a.theta, a.d0, a.dd1, a.dd2, a.dd3, a.dd4);
    }
    grid.sync();
    // ---- P6: g1 = 2*S1@d2 + d1, g3 = 2*S2@d4 + d3 ----
    {
        int xcd = blk & 7, inst = xcd >> 2, sub = xcd & 3;
        int local = (blk >> 3) * 4 + w;
#pragma unroll
        for (int rr = 0; rr < 4; ++rr) {
            int row = sub * 1024 + local * 4 + rr;
            if (inst == 0) spmm_row(a.dd2, a.dd1, a.g1, a.rp1, a.ep1, 2.f, 1.f, row, lane, scol, sval);
            else           spmm_row(a.dd4, a.dd3, a.g3, a.rp2, a.ep2, 2.f, 1.f, row, lane, scol, sval);
        }
    }
    grid.sync();
    // ---- P7: fused final (2 rows/wave) ----
    {
        int local = (blk >> 3) * 4 + w;          // 0..255
#pragma unroll
        for (int rr = 0; rr < 2; ++rr) {
            int row = (blk & 7) * 512 + local * 2 + rr;
            final_row(row, lane, scol, sval, a.g1, a.g3, a.rp1, a.ep1, a.rp2, a.ep2,
                      a.theta, a.d0, a.dd2, a.dd4, a.b_lat, a.out);
        }
    }
}

// ================= fallback kernels (measured r14 structure) =================

__global__ void hist2_kernel(const int* __restrict__ r1, const int* __restrict__ r2,
                             int* __restrict__ cnt1, int* __restrict__ cnt2) {
    int e = blockIdx.x * blockDim.x + threadIdx.x;
    if (e < NNZE) atomicAdd(&cnt1[r1[e]], 1);
    else          atomicAdd(&cnt2[r2[e - NNZE]], 1);
}

__global__ void scan2_kernel(int* cur1, int* rp1, int* cur2, int* rp2) {
    __shared__ int part[256];
    scan_dev(blockIdx.x == 0 ? cur1 : cur2, blockIdx.x == 0 ? rp1 : rp2, part, threadIdx.x);
}

__global__ void util_kernel(const int* __restrict__ r1, const int* __restrict__ c1, const float* __restrict__ v1,
                            const int* __restrict__ r2, const int* __restrict__ c2, const float* __restrict__ v2,
                            int* __restrict__ cur1, int* __restrict__ cur2,
                            int2* __restrict__ ep1, int2* __restrict__ ep2,
                            const float* __restrict__ y, unsigned short* __restrict__ x0h,
                            const float* __restrict__ Wtheta, const float* __restrict__ Whid,
                            const float* __restrict__ Wout,
                            unsigned short* __restrict__ wpa, unsigned short* __restrict__ wpo) {
    int blk = blockIdx.x, t = threadIdx.x;
    if (blk < 512) {
        int e = blk * 256 + t;
        if (e < NNZE) {
            int pos = atomicAdd(&cur1[r1[e]], 1);
            ep1[pos] = make_int2(c1[e] * WD, __float_as_int(v1[e]));
        } else {
            int ee = e - NNZE;
            int pos = atomicAdd(&cur2[r2[ee]], 1);
            ep2[pos] = make_int2(c2[ee] * WD, __float_as_int(v2[ee]));
        }
    } else if (blk < 2560) {
        transA_item((blk - 512) * 256 + t, y, x0h);
    } else {
        prep_dev(t, Wtheta, Whid, Wout, wpa, wpo);
    }
}

struct SpmmDesc {
    const unsigned short* in;
    const unsigned short* prev;
    unsigned short* outH;
    const int* rp; const int2* ep;
    float alpha, beta;
};

__launch_bounds__(64)
__global__ void spmmD_kernel(SpmmDesc q0, SpmmDesc q1) {
    __shared__ int scol[64];
    __shared__ float sval[64];
    int blk = blockIdx.x;                // grid = 2*NN
    int xcd = blk & 7, idx = blk >> 3;
    int inst = xcd >> 2, sub = xcd & 3;
    int row = sub * 1024 + idx;
    const SpmmDesc& q = inst == 0 ? q0 : q1;
    spmm_row(q.in, q.prev, q.outH, q.rp, q.ep, q.alpha, q.beta, row, threadIdx.x, scol, sval);
}

__launch_bounds__(256)
__global__ void proj_fused(const unsigned short* __restrict__ xh,
                           const unsigned short* __restrict__ wpa,
                           const unsigned short* __restrict__ wpo,
                           const float* __restrict__ b_hid,
                           float* __restrict__ theta, float* __restrict__ d0,
                           unsigned short* __restrict__ dd1, unsigned short* __restrict__ dd2,
                           unsigned short* __restrict__ dd3, unsigned short* __restrict__ dd4) {
    __shared__ __align__(16) unsigned short sWa[80 * 104];
    __shared__ __align__(16) unsigned short sWo[80 * 72];
    __shared__ __align__(16) unsigned short sC[4][32 * 72];
    int t = threadIdx.x;
    for (int i = t; i < 1040; i += 256) ((uint4*)sWa)[i] = ((const uint4*)wpa)[i];
    for (int i = t; i < 720; i += 256) ((uint4*)sWo)[i] = ((const uint4*)wpo)[i];
    __syncthreads();
    int lane = t & 63, w = t >> 6;
    int r = lane & 15, g = lane >> 4;
    bf16x8 wfa[5][3];
#pragma unroll
    for (int ct = 0; ct < 5; ++ct)
#pragma unroll
        for (int kt = 0; kt < 3; ++kt)
            wfa[ct][kt] = *(const bf16x8*)(sWa + (ct * 16 + r) * 104 + kt * 32 + g * 8);
    float bh[4];
#pragma unroll
    for (int ct = 0; ct < 4; ++ct) bh[ct] = b_hid[ct * 16 + r];
    unsigned short* myC = (unsigned short*)sC[w];
    for (int i = 0; i < 2; ++i)
        proj_one(blockIdx.x * 8 + w * 2 + i, r, g, wfa, bh, sWo, myC, xh,
                 theta, d0, dd1, dd2, dd3, dd4);
}

__launch_bounds__(64)
__global__ void finalspmm_kernel(const unsigned short* __restrict__ g1, const unsigned short* __restrict__ g3,
                                 const int* __restrict__ rp1, const int2* __restrict__ ep1,
                                 const int* __restrict__ rp2, const int2* __restrict__ ep2,
                                 const float* __restrict__ theta, const float* __restrict__ d0,
                                 const unsigned short* __restrict__ dd2, const unsigned short* __restrict__ dd4,
                                 const float* __restrict__ b_lat, float* __restrict__ out) {
    __shared__ int scol[64];
    __shared__ float sval[64];
    int blk = blockIdx.x;
    int row = (blk & 7) * 512 + (blk >> 3);
    final_row(row, threadIdx.x, scol, sval, g1, g3, rp1, ep1, rp2, ep2,
              theta, d0, dd2, dd4, b_lat, out);
}

// ================= host =================

extern "C" void kernel_launch(void* const* d_in, const int* in_sizes, int n_in,
                              void* d_out, int out_size, void* d_ws, size_t ws_size,
                              hipStream_t stream) {
    const float* y      = (const float*)d_in[1];
    const float* Wtheta = (const float*)d_in[2];
    const float* b_lat  = (const float*)d_in[3];
    const float* Whid   = (const float*)d_in[4];
    const float* b_hid  = (const float*)d_in[5];
    const float* Wout   = (const float*)d_in[6];
    const int*   r1     = (const int*)d_in[7];
    const int*   c1     = (const int*)d_in[8];
    const float* v1     = (const float*)d_in[9];
    const int*   r2     = (const int*)d_in[10];
    const int*   c2     = (const int*)d_in[11];
    const float* v2     = (const float*)d_in[12];
    float* out = (float*)d_out;

    char* ws = (char*)d_ws;
    size_t off = 0;
    auto alloc = [&](size_t bytes) -> char* {
        char* p = ws + off;
        off += (bytes + 255) & ~(size_t)255;
        return p;
    };
    int*   rp1   = (int*)alloc(4097 * 4);
    int*   rp2   = (int*)alloc(4097 * 4);
    int*   cur1  = (int*)alloc(4096 * 4);            // cur1+cur2 contiguous (single memset)
    int*   cur2  = (int*)alloc(4096 * 4);
    int2*  ep1   = (int2*)alloc((size_t)NNZE * 8);
    int2*  ep2   = (int2*)alloc((size_t)NNZE * 8);
    unsigned short* wpa = (unsigned short*)alloc(80 * 104 * 2);
    unsigned short* wpo = (unsigned short*)alloc(80 * 72 * 2);
    unsigned short* xh = (unsigned short*)alloc((size_t)5 * NN * WA * 2);
    float* theta = (float*)alloc((size_t)NN * 512 * 4);
    float* d0    = (float*)alloc((size_t)NN * WD * 4);
    unsigned short* dd1 = (unsigned short*)alloc((size_t)NN * WD * 2);
    unsigned short* dd2 = (unsigned short*)alloc((size_t)NN * WD * 2);
    unsigned short* dd3 = (unsigned short*)alloc((size_t)NN * WD * 2);
    unsigned short* dd4 = (unsigned short*)alloc((size_t)NN * WD * 2);
    unsigned short* g1  = (unsigned short*)alloc((size_t)NN * WD * 2);
    unsigned short* g3  = (unsigned short*)alloc((size_t)NN * WD * 2);
    if (off > ws_size) return;

    unsigned short* x0h = xh;
    unsigned short* x1h = xh + (size_t)1 * NN * WA;
    unsigned short* x2h = xh + (size_t)2 * NN * WA;   // holds y1 = S1@x1
    unsigned short* x3h = xh + (size_t)3 * NN * WA;
    unsigned short* x4h = xh + (size_t)4 * NN * WA;   // holds y3 = S2@x3

    hipMemsetAsync(cur1, 0, 2 * 4096 * 4, stream);

    // ---- try cooperative mega-kernel ----
    static int coop_state = -1;   // -1 unknown, 0 no, 1 yes
    if (coop_state == -1) {
        int dev = 0, coopAttr = 0, nCU = 0, maxPerCU = 0;
        hipGetDevice(&dev);
        hipDeviceGetAttribute(&coopAttr, hipDeviceAttributeCooperativeLaunch, dev);
        hipDeviceGetAttribute(&nCU, hipDeviceAttributeMultiprocessorCount, dev);
        hipError_t oe = hipOccupancyMaxActiveBlocksPerMultiprocessor(&maxPerCU, mega_kernel, 256, 0);
        coop_state = (coopAttr && oe == hipSuccess && maxPerCU * nCU >= MGRID) ? 1 : 0;
    }
    bool ran_coop = false;
    if (coop_state == 1) {
        MegaArgs ma = { r1, c1, v1, r2, c2, v2, cur1, cur2, rp1, rp2, ep1, ep2,
                        y, Wtheta, Whid, Wout, b_hid, b_lat,
                        x0h, x1h, x2h, x3h, x4h, wpa, wpo,
                        theta, d0, dd1, dd2, dd3, dd4, g1, g3, out };
        void* kp[] = { &ma };
        hipError_t le = hipLaunchCooperativeKernel((const void*)mega_kernel,
                                                   dim3(MGRID), dim3(256), kp, 0, stream);
        if (le == hipSuccess) ran_coop = true;
        else coop_state = 0;
    }
    if (ran_coop) return;

    // ---- fallback: measured r14 multi-launch path ----
    hist2_kernel<<<2 * NNZE / 256, 256, 0, stream>>>(r1, r2, cur1, cur2);
    scan2_kernel<<<2, 256, 0, stream>>>(cur1, rp1, cur2, rp2);
    util_kernel<<<2561, 256, 0, stream>>>(r1, c1, v1, r2, c2, v2, cur1, cur2, ep1, ep2,
                                          y, x0h, Wtheta, Whid, Wout, wpa, wpo);
    {
        SpmmDesc a0 = { x0h, nullptr, x1h, rp1, ep1, 1.f, 0.f };
        SpmmDesc a1 = { x0h, nullptr, x3h, rp2, ep2, 1.f, 0.f };
        spmmD_kernel<<<2 * NN, 64, 0, stream>>>(a0, a1);
    }
    {
        SpmmDesc a0 = { x1h, nullptr, x2h, rp1, ep1, 1.f, 0.f };
        SpmmDesc a1 = { x3h, nullptr, x4h, rp2, ep2, 1.f, 0.f };
        spmmD_kernel<<<2 * NN, 64, 0, stream>>>(a0, a1);
    }
    proj_fused<<<NN / 8, 256, 0, stream>>>(xh, wpa, wpo, b_hid,
                                           theta, d0, dd1, dd2, dd3, dd4);
    {
        SpmmDesc a0 = { dd2, dd1, g1, rp1, ep1, 2.f, 1.f };
        SpmmDesc a1 = { dd4, dd3, g3, rp2, ep2, 2.f, 1.f };
        spmmD_kernel<<<2 * NN, 64, 0, stream>>>(a0, a1);
    }
    finalspmm_kernel<<<NN, 64, 0, stream>>>(g1, g3, rp1, ep1, rp2, ep2,
                                            theta, d0, dd2, dd4, b_lat, out);
}